// Round 2
// baseline (496.757 us; speedup 1.0000x reference)
//
#include <hip/hip_runtime.h>
#include <cstdint>

typedef float floatx4 __attribute__((ext_vector_type(4)));

#define D_DIM 256
#define HW 1024
#define K_CODES 1024
#define NPIX 32768          // B*H*W = 32*32*32
#define NELEM 8388608       // B*D*H*W

// output layout (floats): [quantized 8388608][q_loss][e_loss][vq_loss][idx 32768]
#define OFF_QLOSS 8388608
#define OFF_ELOSS 8388609
#define OFF_VQ    8388610
#define OFF_IDX   8388611

// ws layout (bytes)
#define WS_TOP    0          // floatx4 * 2 * 32768 = 1 MB (top-4 per pixel)
#define WS_IDX    1048576    // int * 32768  = 128 KB
#define WS_C2     1179648    // float * 1024 = 4 KB
#define WS_LOSS   1183744    // double       = 8 B

#define MARGIN 1.5e-4f       // covers 2*ulp(340)=6.1e-5 quantization flip window w/ 2.4x slack

// ---- numpy pairwise sum emulation for sum(v*v) over 256 elements ----
// numpy: n=256 -> pairwise(a,128) + pairwise(a+128,128); each 128-block uses
// 8 accumulators r[j] += a[i+j], combined ((r0+r1)+(r2+r3))+((r4+r5)+(r6+r7)).
// __f*_rn intrinsics forbid FMA contraction (must round like numpy's separate ops).
__device__ __forceinline__ float np_pairwise_sq_256(const float* __restrict__ a, int stride) {
    float half[2];
#pragma unroll
    for (int h = 0; h < 2; ++h) {
        const float* p = a + (size_t)(h * 128) * stride;
        float r[8];
#pragma unroll
        for (int j = 0; j < 8; ++j) { float t = p[(size_t)j * stride]; r[j] = __fmul_rn(t, t); }
        for (int i = 8; i < 128; i += 8)
#pragma unroll
            for (int j = 0; j < 8; ++j) {
                float t = p[(size_t)(i + j) * stride];
                r[j] = __fadd_rn(r[j], __fmul_rn(t, t));
            }
        half[h] = __fadd_rn(__fadd_rn(__fadd_rn(r[0], r[1]), __fadd_rn(r[2], r[3])),
                            __fadd_rn(__fadd_rn(r[4], r[5]), __fadd_rn(r[6], r[7])));
    }
    return __fadd_rn(half[0], half[1]);
}

// ---------------- kernel 0: codebook row norms, numpy-pairwise fp32 ----------------
__global__ __launch_bounds__(256) void c2_kernel(const float* __restrict__ cb,
                                                 float* __restrict__ c2) {
    int k = blockIdx.x * 256 + threadIdx.x;
    if (k >= K_CODES) return;
    c2[k] = np_pairwise_sq_256(cb + (size_t)k * D_DIM, 1);
}

// ---------------- kernel 1: fp32 GEMM + per-pixel top-4 ----------------
#define TPX 64
#define TKC 128
#define NKC (K_CODES / TKC)   // 8
#define TDC 64
#define NDC (D_DIM / TDC)     // 4

__device__ __forceinline__ void upd2(float v, int k, float& M1, int& I1,
                                     float& M2, int& I2) {
    if (v < M1 || (v == M1 && k < I1)) { M2 = M1; I2 = I1; M1 = v; I1 = k; }
    else if (v < M2 || (v == M2 && k < I2)) { M2 = v; I2 = k; }
}

__device__ __forceinline__ void ins4(float v, int k, float* S, int* I) {
    if (v < S[3] || (v == S[3] && k < I[3])) {
        S[3] = v; I[3] = k;
#pragma unroll
        for (int j = 3; j > 0; --j) {
            bool sw = (S[j] < S[j - 1]) || (S[j] == S[j - 1] && I[j] < I[j - 1]);
            if (sw) {
                float ts = S[j]; S[j] = S[j - 1]; S[j - 1] = ts;
                int   ti = I[j]; I[j] = I[j - 1]; I[j - 1] = ti;
            }
        }
    }
}

__global__ __launch_bounds__(256) void gemm_top_kernel(
        const float* __restrict__ x, const float* __restrict__ cb,
        const float* __restrict__ c2, floatx4* __restrict__ top) {
    __shared__ float Xs[TDC][TPX];   // 16 KB, [dd][p] — matches NCHW, no transpose
    __shared__ float Cs[TKC][TDC];   // 32 KB, [c][swizzled d-quads]

    const int t  = threadIdx.x;
    const int tx = t & 15;           // code group: 8 codes
    const int ty = t >> 4;           // pixel group: 4 pixels
    const int tile = blockIdx.x;     // 0..511
    const int bimg = tile >> 4;
    const int hw0  = (tile & 15) * TPX;
    const float* xbase = x + (size_t)bimg * D_DIM * HW + hw0;

    float m1[4], m2[4]; int i1[4], i2[4];
#pragma unroll
    for (int a = 0; a < 4; ++a) { m1[a] = INFINITY; m2[a] = INFINITY; i1[a] = 0; i2[a] = 0; }

    for (int kc = 0; kc < NKC; ++kc) {
        const int k0 = kc * TKC;
        float acc[4][8];
#pragma unroll
        for (int a = 0; a < 4; ++a)
#pragma unroll
            for (int i = 0; i < 8; ++i) acc[a][i] = 0.f;

        for (int dc = 0; dc < NDC; ++dc) {
            __syncthreads();   // protect LDS from previous chunk's readers
            // stage X[dd][p]: coalesced float4 over p
            {
                const int p4 = (t & 15) * 4;
                const int ddb = t >> 4;
#pragma unroll
                for (int r = 0; r < 4; ++r) {
                    int dd = r * 16 + ddb;
                    floatx4 v = *(const floatx4*)(xbase + (size_t)(dc * TDC + dd) * HW + p4);
                    *(floatx4*)&Xs[dd][p4] = v;
                }
            }
            // stage C[c][dq^s]: coalesced float4 over d, swizzled quads
            {
                const int dq = t & 15;
                const int cg = t >> 4;
#pragma unroll
                for (int jj = 0; jj < 8; ++jj) {
                    int c = jj * 16 + cg;
                    floatx4 v = *(const floatx4*)(cb + (size_t)(k0 + c) * D_DIM + dc * TDC + dq * 4);
                    int s = (c >> 3) & 15;
                    *(floatx4*)&Cs[c][4 * (dq ^ s)] = v;
                }
            }
            __syncthreads();
#pragma unroll 4
            for (int dq = 0; dq < 16; ++dq) {
                floatx4 xv[4], cv[8];
#pragma unroll
                for (int j = 0; j < 4; ++j) xv[j] = *(const floatx4*)&Xs[4 * dq + j][ty * 4];
#pragma unroll
                for (int i = 0; i < 8; ++i) cv[i] = *(const floatx4*)&Cs[tx * 8 + i][4 * (dq ^ tx)];
#pragma unroll
                for (int i = 0; i < 8; ++i)
#pragma unroll
                    for (int j = 0; j < 4; ++j)
#pragma unroll
                        for (int a = 0; a < 4; ++a)
                            acc[a][i] = fmaf(xv[j][a], cv[i][j], acc[a][i]);
            }
        }
        // score s = c2 - 2*dot, update local top-2
#pragma unroll
        for (int i = 0; i < 8; ++i) {
            int kg = k0 + tx * 8 + i;
            float c2v = c2[kg];
#pragma unroll
            for (int a = 0; a < 4; ++a) {
                float s = fmaf(-2.f, acc[a][i], c2v);
                upd2(s, kg, m1[a], i1[a], m2[a], i2[a]);
            }
        }
    }

    // merge 16 tx-partials (top-2 each) per pixel into global top-4 via LDS
    __syncthreads();
    floatx4* scratch = (floatx4*)&Cs[0][0];   // 64 px * 16 tx * 16B = 16 KB
#pragma unroll
    for (int a = 0; a < 4; ++a)
        scratch[(ty * 4 + a) * 16 + tx] = floatx4{m1[a], (float)i1[a], m2[a], (float)i2[a]};
    __syncthreads();
    if (t < TPX) {
        float S[4] = {INFINITY, INFINITY, INFINITY, INFINITY};
        int   I[4] = {0x7fffffff, 0x7fffffff, 0x7fffffff, 0x7fffffff};
#pragma unroll
        for (int q = 0; q < 16; ++q) {
            floatx4 e = scratch[t * 16 + q];
            ins4(e[0], (int)e[1], S, I);
            ins4(e[2], (int)e[3], S, I);
        }
        int P = tile * TPX + t;   // == global pixel index
        top[2 * P]     = floatx4{S[0], (float)I[0], S[1], (float)I[1]};
        top[2 * P + 1] = floatx4{S[2], (float)I[2], S[3], (float)I[3]};
    }
}

// ---------------- kernel 2: emulate reference fp32 d2 on near-ties ----------------
// ref (numpy fp32): d2_k = fl(fl(x2 - fl(2*mm_k)) + c2_k); argmin, first-index tie-break.
// x2 at scale ~256 quantizes scores to ulp ~3.05e-5 — this DECIDES ~200 pixels.
__global__ __launch_bounds__(256) void rescore_kernel(
        const float* __restrict__ x, const float* __restrict__ cb,
        const float* __restrict__ c2, const floatx4* __restrict__ top,
        float* __restrict__ out_idx, int* __restrict__ idxbuf) {
    int P = blockIdx.x * 256 + threadIdx.x;
    if (P >= NPIX) return;
    floatx4 ta = top[2 * P];
    floatx4 tb = top[2 * P + 1];
    int best = (int)ta[1];
    float s1 = ta[0];
    if (ta[2] - s1 <= MARGIN) {
        float cs[4] = {ta[0], ta[2], tb[0], tb[2]};
        int   ck[4] = {(int)ta[1], (int)ta[3], (int)tb[1], (int)tb[3]};
        int nc = 1;
        while (nc < 4 && cs[nc] - s1 <= MARGIN) ++nc;

        const float* xb = x + (size_t)(P >> 10) * D_DIM * HW + (P & 1023);
        float x2 = np_pairwise_sq_256(xb, HW);

        const float* cr[4];
#pragma unroll
        for (int j = 0; j < 4; ++j) cr[j] = cb + (size_t)ck[j < nc ? j : 0] * D_DIM;
        double acc[4] = {0.0, 0.0, 0.0, 0.0};
        for (int d = 0; d < D_DIM; ++d) {
            double xv = (double)xb[(size_t)d * HW];
#pragma unroll
            for (int j = 0; j < 4; ++j) acc[j] += xv * (double)cr[j][d];
        }
        float bd = INFINITY; int bi = 0x7fffffff;
        for (int j = 0; j < nc; ++j) {
            float mm = (float)acc[j];                              // RN(exact) ~ any faithful sgemm
            float t1 = __fsub_rn(x2, __fmul_rn(2.0f, mm));         // fl(x2 - 2*mm)
            float Dq = __fadd_rn(t1, c2[ck[j]]);                   // fl(... + c2)
            if (Dq < bd || (Dq == bd && ck[j] < bi)) { bd = Dq; bi = ck[j]; }
        }
        best = bi;
    }
    idxbuf[P] = best;
    out_idx[P] = (float)best;
}

// ---------------- kernel 3: quantized write + loss partial sums ----------------
__global__ __launch_bounds__(128) void quantize_loss_kernel(
        const float* __restrict__ x, const float* __restrict__ cb,
        const int* __restrict__ idxbuf, float* __restrict__ out_q,
        double* __restrict__ lossAcc) {
    int P = blockIdx.x * 128 + threadIdx.x;
    int bimg = P >> 10, hw = P & 1023;
    const float* xb = x + (size_t)bimg * D_DIM * HW + hw;
    float* qb = out_q + (size_t)bimg * D_DIM * HW + hw;
    const floatx4* crow = (const floatx4*)(cb + (size_t)idxbuf[P] * D_DIM);
    float lsum = 0.f;
#pragma unroll 4
    for (int d4 = 0; d4 < D_DIM / 4; ++d4) {
        floatx4 q = crow[d4];   // row gather, L2-resident codebook
#pragma unroll
        for (int j = 0; j < 4; ++j) {
            size_t off = (size_t)(d4 * 4 + j) * HW;
            float xv = xb[off];
            qb[off] = q[j];             // coalesced store
            float df = q[j] - xv;
            lsum = fmaf(df, df, lsum);
        }
    }
    double ds = (double)lsum;
#pragma unroll
    for (int off = 32; off > 0; off >>= 1) ds += __shfl_down(ds, off);
    __shared__ double sred[2];
    if ((threadIdx.x & 63) == 0) sred[threadIdx.x >> 6] = ds;
    __syncthreads();
    if (threadIdx.x == 0) atomicAdd(lossAcc, sred[0] + sred[1]);
}

// ---------------- kernel 4: loss scalars ----------------
__global__ void finalize_loss(const double* __restrict__ lossAcc,
                              float* __restrict__ out) {
    double m = *lossAcc / (double)NELEM;
    out[OFF_QLOSS] = (float)m;
    out[OFF_ELOSS] = (float)m;            // numerically identical to q_loss
    out[OFF_VQ]    = (float)(1.25 * m);   // q_loss + BETA*e_loss, BETA=0.25
}

extern "C" void kernel_launch(void* const* d_in, const int* in_sizes, int n_in,
                              void* d_out, int out_size, void* d_ws, size_t ws_size,
                              hipStream_t stream) {
    const float* x  = (const float*)d_in[0];   // (32,256,32,32)
    const float* cb = (const float*)d_in[1];   // (1024,256)
    float* out = (float*)d_out;
    char* ws = (char*)d_ws;

    floatx4* top    = (floatx4*)(ws + WS_TOP);
    int*     idxbuf = (int*)(ws + WS_IDX);
    float*   c2     = (float*)(ws + WS_C2);
    double*  lossAcc= (double*)(ws + WS_LOSS);

    hipMemsetAsync(lossAcc, 0, sizeof(double), stream);
    c2_kernel<<<4, 256, 0, stream>>>(cb, c2);
    gemm_top_kernel<<<512, 256, 0, stream>>>(x, cb, c2, top);
    rescore_kernel<<<NPIX / 256, 256, 0, stream>>>(x, cb, c2, top, out + OFF_IDX, idxbuf);
    quantize_loss_kernel<<<NPIX / 128, 128, 0, stream>>>(x, cb, idxbuf, out, lossAcc);
    finalize_loss<<<1, 1, 0, stream>>>(lossAcc, out);
}

// Round 3
// 317.658 us; speedup vs baseline: 1.5638x; 1.5638x over previous
//
#include <hip/hip_runtime.h>
#include <cstdint>

typedef float floatx4 __attribute__((ext_vector_type(4)));
typedef _Float16 half8 __attribute__((ext_vector_type(8)));
typedef _Float16 half4v __attribute__((ext_vector_type(4)));

#define D_DIM 256
#define HW 1024
#define K_CODES 1024
#define NPIX 32768          // B*H*W = 32*32*32
#define NELEM 8388608       // B*D*H*W

// output layout (floats): [quantized 8388608][q_loss][e_loss][vq_loss][idx 32768]
#define OFF_QLOSS 8388608
#define OFF_ELOSS 8388609
#define OFF_VQ    8388610
#define OFF_IDX   8388611

// ws layout (bytes)
#define WS_TOP    0          // floatx4 * 2 * 32768 = 1 MB (top-4 per pixel)
#define WS_IDX    1048576    // int * 32768  = 128 KB
#define WS_C2     1179648    // float * 1024 = 4 KB
#define WS_LOSS   1183744    // double       = 8 B

// fp16 scratch lives in d_out's quantized region (overwritten at the end):
//   xt16: [32768 px][256 d] halves = 16.78 MB at out+0
//   cb16: [1024 c][256 d] halves (scaled x1024) = 0.52 MB after xt16
// total 17.3 MB < 33.5 MB quantized region.

// margin: fp32-ref quantization window ~6.1e-5 + 2*fp16-GEMM error (<5e-5) + slack
#define MARGIN 2.5e-4f

// ---- numpy pairwise sum emulation for sum(v*v) over 256 elements ----
__device__ __forceinline__ float np_pairwise_sq_256(const float* __restrict__ a, int stride) {
    float half[2];
#pragma unroll
    for (int h = 0; h < 2; ++h) {
        const float* p = a + (size_t)(h * 128) * stride;
        float r[8];
#pragma unroll
        for (int j = 0; j < 8; ++j) { float t = p[(size_t)j * stride]; r[j] = __fmul_rn(t, t); }
        for (int i = 8; i < 128; i += 8)
#pragma unroll
            for (int j = 0; j < 8; ++j) {
                float t = p[(size_t)(i + j) * stride];
                r[j] = __fadd_rn(r[j], __fmul_rn(t, t));
            }
        half[h] = __fadd_rn(__fadd_rn(__fadd_rn(r[0], r[1]), __fadd_rn(r[2], r[3])),
                            __fadd_rn(__fadd_rn(r[4], r[5]), __fadd_rn(r[6], r[7])));
    }
    return __fadd_rn(half[0], half[1]);
}

// ---------------- kernel 0: codebook row norms, numpy-pairwise fp32 ----------------
__global__ __launch_bounds__(256) void c2_kernel(const float* __restrict__ cb,
                                                 float* __restrict__ c2) {
    int k = blockIdx.x * 256 + threadIdx.x;
    if (k >= K_CODES) return;
    c2[k] = np_pairwise_sq_256(cb + (size_t)k * D_DIM, 1);
}

// ---------------- kernel A: transpose-convert x (NCHW fp32 -> [px][d] fp16) --------
__global__ __launch_bounds__(256) void convert_x_kernel(const float* __restrict__ x,
                                                        _Float16* __restrict__ xt) {
    __shared__ float Ts[64][65];
    const int t = threadIdx.x;
    const int blk = blockIdx.x;          // 2048 = 32 b * 4 dblk * 16 hwblk
    const int b = blk >> 6;
    const int dblk = (blk >> 4) & 3;
    const int hwblk = blk & 15;
    const int d0 = dblk * 64, hw0 = hwblk * 64;
    const float* xb = x + ((size_t)b * D_DIM + d0) * HW + hw0;
    {
        int dd = t >> 4;
        int c4 = (t & 15) * 4;
#pragma unroll
        for (int rr = 0; rr < 4; ++rr) {
            int dl = rr * 16 + dd;
            floatx4 v = *(const floatx4*)(xb + (size_t)dl * HW + c4);
            Ts[dl][c4] = v[0]; Ts[dl][c4 + 1] = v[1];
            Ts[dl][c4 + 2] = v[2]; Ts[dl][c4 + 3] = v[3];
        }
    }
    __syncthreads();
    {
        int d4 = (t & 15) * 4;
        int hh = t >> 4;
#pragma unroll
        for (int cc = 0; cc < 4; ++cc) {
            int hwl = cc * 16 + hh;
            int px = b * HW + hw0 + hwl;
            half4v o;
#pragma unroll
            for (int j = 0; j < 4; ++j) o[j] = (_Float16)Ts[d4 + j][hwl];
            *(half4v*)(xt + (size_t)px * D_DIM + d0 + d4) = o;
        }
    }
}

// ---------------- kernel B: convert codebook fp32 -> fp16, scaled by 2^10 ----------
// cb values are ~1e-3 (fp16 subnormal territory); x1024 (exact) keeps them normal.
__global__ __launch_bounds__(256) void convert_cb_kernel(const float* __restrict__ cb,
                                                         _Float16* __restrict__ cbh) {
    int i = (blockIdx.x * 256 + threadIdx.x) * 4;
    floatx4 v = *(const floatx4*)(cb + i);
    half4v o;
#pragma unroll
    for (int j = 0; j < 4; ++j) o[j] = (_Float16)(v[j] * 1024.0f);
    *(half4v*)(cbh + i) = o;
}

// ---------------- kernel 1: fp16 MFMA GEMM + per-pixel top-4 ----------------
// A = codes (rows), B = pixels (cols). D[row=code][col=px] per MFMA C/D layout.
// Block: 64 px x 1024 codes, 4 passes of 256 codes; d-chunks of 128.
// Wave tile: 64 codes x 64 px = 16 mfma per K-step, 8 ds_read_b128.
__device__ __forceinline__ void upd2v(float v, int k, float& M1, int& I1,
                                      float& M2, int& I2) {
    // ties land inside MARGIN and are resolved by the rescore kernel; no index tiebreak
    if (v < M1) { M2 = M1; I2 = I1; M1 = v; I1 = k; }
    else if (v < M2) { M2 = v; I2 = k; }
}

__device__ __forceinline__ void ins4v(float v, int k, float* S, int* I) {
    if (v < S[3]) {
        S[3] = v; I[3] = k;
#pragma unroll
        for (int j = 3; j > 0; --j) {
            if (S[j] < S[j - 1]) {
                float ts = S[j]; S[j] = S[j - 1]; S[j - 1] = ts;
                int   ti = I[j]; I[j] = I[j - 1]; I[j - 1] = ti;
            }
        }
    }
}

__global__ __launch_bounds__(256, 2) void gemm_top_mfma(
        const _Float16* __restrict__ xt, const _Float16* __restrict__ cbh,
        const float* __restrict__ c2, floatx4* __restrict__ top) {
    __shared__ _Float16 Ps[64][128];    // 16 KB: pixels [px][d-chunk], XOR-swizzled 16B blocks
    __shared__ _Float16 Cs[256][128];   // 64 KB: codes  [c][d-chunk],  XOR-swizzled 16B blocks

    const int t = threadIdx.x;
    const int w = t >> 6;        // wave 0..3
    const int l = t & 63;        // lane
    const int l15 = l & 15;
    const int lq = l >> 4;       // quad 0..3
    const int P0 = blockIdx.x * 64;   // pixel base

    // running top-4 (wave 0 lanes only; lane = px)
    float S[4] = {INFINITY, INFINITY, INFINITY, INFINITY};
    int   I[4] = {0x7fffffff, 0x7fffffff, 0x7fffffff, 0x7fffffff};
    floatx4* scr = (floatx4*)&Ps[0][0];   // 64 px * 16 partials * 16B = 16384 B (== Ps)
    const int part = w * 4 + lq;

#pragma unroll
    for (int pass = 0; pass < 4; ++pass) {
        floatx4 acc[4][4];
#pragma unroll
        for (int i = 0; i < 4; ++i)
#pragma unroll
            for (int j = 0; j < 4; ++j) acc[i][j] = floatx4{0.f, 0.f, 0.f, 0.f};

#pragma unroll
        for (int dc = 0; dc < 2; ++dc) {
            __syncthreads();   // previous readers (compute / scr merge) done
            // stage Ps: 16 KB = 4 rounds x (256 thr x 16B); row r, 16B-block sd
            {
                int r = t >> 4;               // px row 0..15 (+16 per round)
                int gb = t & 15;              // global 16B block within 128-d chunk
#pragma unroll
                for (int rr = 0; rr < 4; ++rr) {
                    int row = rr * 16 + r;
                    floatx4 v = *(const floatx4*)(xt + (size_t)(P0 + row) * D_DIM + dc * 128 + gb * 8);
                    int sd = gb ^ (row & 7);
                    *(floatx4*)&Ps[row][sd * 8] = v;
                }
            }
            // stage Cs: 64 KB = 16 rounds
            {
                int r = t >> 4;
                int gb = t & 15;
#pragma unroll
                for (int rr = 0; rr < 16; ++rr) {
                    int row = rr * 16 + r;
                    floatx4 v = *(const floatx4*)(cbh + (size_t)(pass * 256 + row) * D_DIM + dc * 128 + gb * 8);
                    int sd = gb ^ (row & 7);
                    *(floatx4*)&Cs[row][sd * 8] = v;
                }
            }
            __syncthreads();
            // compute: 4 K-steps of 32
#pragma unroll
            for (int ks = 0; ks < 4; ++ks) {
                const int sdq = (ks * 4 + lq) ^ (l15 & 7);   // swizzled 16B block
                half8 a[4], b[4];
#pragma unroll
                for (int i = 0; i < 4; ++i)
                    a[i] = *(const half8*)&Cs[w * 64 + i * 16 + l15][sdq * 8];
#pragma unroll
                for (int j = 0; j < 4; ++j)
                    b[j] = *(const half8*)&Ps[j * 16 + l15][sdq * 8];
#pragma unroll
                for (int i = 0; i < 4; ++i)
#pragma unroll
                    for (int j = 0; j < 4; ++j)
                        acc[i][j] = __builtin_amdgcn_mfma_f32_16x16x32_f16(a[i], b[j], acc[i][j], 0, 0, 0);
            }
        }

        // epilogue: s = c2 - acc/512 (cb was scaled x1024; 2*dot = acc/512, exact pow2)
        float m1[4] = {INFINITY, INFINITY, INFINITY, INFINITY};
        float m2[4] = {INFINITY, INFINITY, INFINITY, INFINITY};
        int   i1[4] = {0, 0, 0, 0}, i2[4] = {0, 0, 0, 0};
#pragma unroll
        for (int i = 0; i < 4; ++i) {
            int cbase = pass * 256 + w * 64 + i * 16 + lq * 4;
            floatx4 c2v = *(const floatx4*)&c2[cbase];
#pragma unroll
            for (int r = 0; r < 4; ++r) {
#pragma unroll
                for (int j = 0; j < 4; ++j) {
                    float s = fmaf(-0.001953125f, acc[i][j][r], c2v[r]);
                    upd2v(s, cbase + r, m1[j], i1[j], m2[j], i2[j]);
                }
            }
        }
        // merge this pass's partials (top-2 over 16-code subsets) via scr
        __syncthreads();   // all waves done reading Ps for this pass
#pragma unroll
        for (int j = 0; j < 4; ++j) {
            int px = j * 16 + l15;
            scr[px * 16 + ((part + px) & 15)] =
                floatx4{m1[j], (float)i1[j], m2[j], (float)i2[j]};
        }
        __syncthreads();
        if (w == 0) {
            int px = l;   // 0..63
#pragma unroll
            for (int p = 0; p < 16; ++p) {
                floatx4 e = scr[px * 16 + ((p + px) & 15)];
                ins4v(e[0], (int)e[1], S, I);
                ins4v(e[2], (int)e[3], S, I);
            }
        }
        // next pass's dc-loop barrier protects scr (=Ps) before restaging
    }

    if (w == 0) {
        int P = P0 + l;
        top[2 * P]     = floatx4{S[0], (float)I[0], S[1], (float)I[1]};
        top[2 * P + 1] = floatx4{S[2], (float)I[2], S[3], (float)I[3]};
    }
}

// ---------------- kernel 2: emulate reference fp32 d2 on near-ties ----------------
__global__ __launch_bounds__(256) void rescore_kernel(
        const float* __restrict__ x, const float* __restrict__ cb,
        const float* __restrict__ c2, const floatx4* __restrict__ top,
        float* __restrict__ out_idx, int* __restrict__ idxbuf) {
    int P = blockIdx.x * 256 + threadIdx.x;
    if (P >= NPIX) return;
    floatx4 ta = top[2 * P];
    floatx4 tb = top[2 * P + 1];
    int best = (int)ta[1];
    float s1 = ta[0];
    if (ta[2] - s1 <= MARGIN) {
        float cs[4] = {ta[0], ta[2], tb[0], tb[2]};
        int   ck[4] = {(int)ta[1], (int)ta[3], (int)tb[1], (int)tb[3]};
        int nc = 1;
        while (nc < 4 && cs[nc] - s1 <= MARGIN) ++nc;

        const float* xb = x + (size_t)(P >> 10) * D_DIM * HW + (P & 1023);
        float x2 = np_pairwise_sq_256(xb, HW);

        const float* cr[4];
#pragma unroll
        for (int j = 0; j < 4; ++j) cr[j] = cb + (size_t)ck[j < nc ? j : 0] * D_DIM;
        double acc[4] = {0.0, 0.0, 0.0, 0.0};
        for (int d = 0; d < D_DIM; ++d) {
            double xv = (double)xb[(size_t)d * HW];
#pragma unroll
            for (int j = 0; j < 4; ++j) acc[j] += xv * (double)cr[j][d];
        }
        float bd = INFINITY; int bi = 0x7fffffff;
        for (int j = 0; j < nc; ++j) {
            float mm = (float)acc[j];                              // RN(exact) ~ faithful sgemm
            float t1 = __fsub_rn(x2, __fmul_rn(2.0f, mm));         // fl(x2 - 2*mm)
            float Dq = __fadd_rn(t1, c2[ck[j]]);                   // fl(... + c2)
            if (Dq < bd || (Dq == bd && ck[j] < bi)) { bd = Dq; bi = ck[j]; }
        }
        best = bi;
    }
    idxbuf[P] = best;
    out_idx[P] = (float)best;
}

// ---------------- kernel 3: quantized write + loss partial sums ----------------
__global__ __launch_bounds__(128) void quantize_loss_kernel(
        const float* __restrict__ x, const float* __restrict__ cb,
        const int* __restrict__ idxbuf, float* __restrict__ out_q,
        double* __restrict__ lossAcc) {
    int P = blockIdx.x * 128 + threadIdx.x;
    int bimg = P >> 10, hw = P & 1023;
    const float* xb = x + (size_t)bimg * D_DIM * HW + hw;
    float* qb = out_q + (size_t)bimg * D_DIM * HW + hw;
    const floatx4* crow = (const floatx4*)(cb + (size_t)idxbuf[P] * D_DIM);
    float lsum = 0.f;
#pragma unroll 4
    for (int d4 = 0; d4 < D_DIM / 4; ++d4) {
        floatx4 q = crow[d4];
#pragma unroll
        for (int j = 0; j < 4; ++j) {
            size_t off = (size_t)(d4 * 4 + j) * HW;
            float xv = xb[off];
            qb[off] = q[j];
            float df = q[j] - xv;
            lsum = fmaf(df, df, lsum);
        }
    }
    double ds = (double)lsum;
#pragma unroll
    for (int off = 32; off > 0; off >>= 1) ds += __shfl_down(ds, off);
    __shared__ double sred[2];
    if ((threadIdx.x & 63) == 0) sred[threadIdx.x >> 6] = ds;
    __syncthreads();
    if (threadIdx.x == 0) atomicAdd(lossAcc, sred[0] + sred[1]);
}

// ---------------- kernel 4: loss scalars ----------------
__global__ void finalize_loss(const double* __restrict__ lossAcc,
                              float* __restrict__ out) {
    double m = *lossAcc / (double)NELEM;
    out[OFF_QLOSS] = (float)m;
    out[OFF_ELOSS] = (float)m;
    out[OFF_VQ]    = (float)(1.25 * m);
}

extern "C" void kernel_launch(void* const* d_in, const int* in_sizes, int n_in,
                              void* d_out, int out_size, void* d_ws, size_t ws_size,
                              hipStream_t stream) {
    const float* x  = (const float*)d_in[0];   // (32,256,32,32)
    const float* cb = (const float*)d_in[1];   // (1024,256)
    float* out = (float*)d_out;
    char* ws = (char*)d_ws;

    floatx4* top    = (floatx4*)(ws + WS_TOP);
    int*     idxbuf = (int*)(ws + WS_IDX);
    float*   c2     = (float*)(ws + WS_C2);
    double*  lossAcc= (double*)(ws + WS_LOSS);

    // fp16 scratch in the quantized-output region (overwritten by kernel 3)
    _Float16* xt16 = (_Float16*)out;                    // 32768*256 halves
    _Float16* cb16 = xt16 + (size_t)NPIX * D_DIM;       // 1024*256 halves

    hipMemsetAsync(lossAcc, 0, sizeof(double), stream);
    convert_x_kernel<<<2048, 256, 0, stream>>>(x, xt16);
    convert_cb_kernel<<<256, 256, 0, stream>>>(cb, cb16);
    c2_kernel<<<4, 256, 0, stream>>>(cb, c2);
    gemm_top_mfma<<<512, 256, 0, stream>>>(xt16, cb16, c2, top);
    rescore_kernel<<<NPIX / 256, 256, 0, stream>>>(x, cb, c2, top, out + OFF_IDX, idxbuf);
    quantize_loss_kernel<<<NPIX / 128, 128, 0, stream>>>(x, cb, idxbuf, out, lossAcc);
    finalize_loss<<<1, 1, 0, stream>>>(lossAcc, out);
}

// Round 4
// 189.113 us; speedup vs baseline: 2.6268x; 1.6797x over previous
//
#include <hip/hip_runtime.h>
#include <cstdint>

typedef float floatx4 __attribute__((ext_vector_type(4)));
typedef _Float16 half8 __attribute__((ext_vector_type(8)));
typedef _Float16 half4v __attribute__((ext_vector_type(4)));

#define D_DIM 256
#define HW 1024
#define K_CODES 1024
#define NPIX 32768          // B*H*W
#define NELEM 8388608       // B*D*H*W

// output layout (floats): [quantized 8388608][q_loss][e_loss][vq_loss][idx 32768]
#define OFF_QLOSS 8388608
#define OFF_ELOSS 8388609
#define OFF_VQ    8388610
#define OFF_IDX   8388611

// ws layout (bytes) — total 432 KB, well under the proven 1.18 MB
#define WS_IDX     0         // int * 32768 = 131072
#define WS_C2      131072    // float * 1024 = 4096
#define WS_CNT     135168    // int (+pad) = 64
#define WS_PART    135232    // double * 256 = 2048
#define WS_FLAGPX  137280    // int * 8192 = 32768
#define WS_FLAGTOP 170048    // floatx4 * 2 * 8192 = 262144 (16B aligned)
#define FLAG_CAP   8192      // expected flags ~1.5K; cap is >100 sigma out

// fp16 codebook scratch lives at d_out+0 (quantized region, overwritten later)

#define MARGIN 2.5e-4f       // ref fp32-quantization window ~6.1e-5 + fp16 GEMM err, with slack

// ---- numpy pairwise sum emulation for sum(v*v) over 256 elements ----
__device__ __forceinline__ float np_pairwise_sq_256(const float* __restrict__ a, int stride) {
    float half[2];
#pragma unroll
    for (int h = 0; h < 2; ++h) {
        const float* p = a + (size_t)(h * 128) * stride;
        float r[8];
#pragma unroll
        for (int j = 0; j < 8; ++j) { float t = p[(size_t)j * stride]; r[j] = __fmul_rn(t, t); }
        for (int i = 8; i < 128; i += 8)
#pragma unroll
            for (int j = 0; j < 8; ++j) {
                float t = p[(size_t)(i + j) * stride];
                r[j] = __fadd_rn(r[j], __fmul_rn(t, t));
            }
        half[h] = __fadd_rn(__fadd_rn(__fadd_rn(r[0], r[1]), __fadd_rn(r[2], r[3])),
                            __fadd_rn(__fadd_rn(r[4], r[5]), __fadd_rn(r[6], r[7])));
    }
    return __fadd_rn(half[0], half[1]);
}

// ---------------- kernel 0: prep — cb->fp16(x1024), c2 norms, zero flag count ------
__global__ __launch_bounds__(256) void prep_kernel(const float* __restrict__ cb,
                                                   _Float16* __restrict__ cbh,
                                                   float* __restrict__ c2,
                                                   int* __restrict__ cnt) {
    int b = blockIdx.x;
    if (b < 256) {
        int i = (b * 256 + threadIdx.x) * 4;
        floatx4 v = *(const floatx4*)(cb + i);
        half4v o;
#pragma unroll
        for (int j = 0; j < 4; ++j) o[j] = (_Float16)(v[j] * 1024.0f);  // exact pow2 scale
        *(half4v*)(cbh + i) = o;
    } else {
        if (b == 256 && threadIdx.x == 0) *cnt = 0;
        int k = (b - 256) * 256 + threadIdx.x;   // blocks 256..259 -> rows 0..1023
        c2[k] = np_pairwise_sq_256(cb + (size_t)k * D_DIM, 1);
    }
}

// top-4 insert, no index tiebreak (ties resolved by rescore)
__device__ __forceinline__ void ins4v(float v, int k, float* S, int* I) {
    if (v < S[3]) {
        S[3] = v; I[3] = k;
#pragma unroll
        for (int j = 3; j > 0; --j) {
            if (S[j] < S[j - 1]) {
                float ts = S[j]; S[j] = S[j - 1]; S[j - 1] = ts;
                int   ti = I[j]; I[j] = I[j - 1]; I[j - 1] = ti;
            }
        }
    }
}

// ---------------- kernel 1: barrier-free MFMA stream GEMM + top-4 + flag list -------
// Wave = 32 px (A-frags in regs), streams 512 codes (half) from L2, 16/chunk,
// double-buffered B regs. Block = 4 waves = 64 px x all 1024 codes. No LDS in loop.
__global__ __launch_bounds__(256, 2) void gemm_stream(
        const float* __restrict__ x, const _Float16* __restrict__ cbh,
        const float* __restrict__ c2, float* __restrict__ out_idx,
        int* __restrict__ idxbuf, int* __restrict__ cnt,
        int* __restrict__ flagPx, floatx4* __restrict__ flagTop) {
    __shared__ float scr[4][32 * 65];   // SoA [m1|i1|m2|i2][part][px pad65] = 33 KB

    const int t = threadIdx.x;
    const int w = t >> 6;
    const int l = t & 63;
    const int l15 = l & 15;
    const int q = l >> 4;
    const int pxg = w >> 1;          // pixel group 0/1 (32 px each)
    const int half = w & 1;          // code half 0/1 (512 codes each)
    const int px0 = blockIdx.x * 64;
    const int bimg = px0 >> 10;      // 64-px blocks never straddle images
    const int hwb = (px0 & 1023) + pxg * 32;
    const float* xb = x + (size_t)bimg * (D_DIM * HW);

    // ---- load A: 32 px x 256 d from fp32 NCHW, convert to f16 frags in regs ----
    // A[m=l15][k=q*8+j] per 16x16x32 layout; d = s*32 + q*8 + j
    half8 A[2][8];
#pragma unroll
    for (int r = 0; r < 2; ++r) {
        float tmp[64];
#pragma unroll
        for (int s = 0; s < 8; ++s)
#pragma unroll
            for (int j = 0; j < 8; ++j)
                tmp[s * 8 + j] = xb[(size_t)(s * 32 + q * 8 + j) * HW + hwb + r * 16 + l15];
#pragma unroll
        for (int s = 0; s < 8; ++s) {
            half8 h;
#pragma unroll
            for (int j = 0; j < 8; ++j) h[j] = (_Float16)tmp[s * 8 + j];
            A[r][s] = h;
        }
    }

    // ---- stream codes: B[n=l15][k=q*8+j], row = half*512 + ch*16 + l15 ----
    const _Float16* cbase = cbh + (size_t)(half * 512 + l15) * D_DIM;
    half8 B[2][8];
#pragma unroll
    for (int s = 0; s < 8; ++s)
        B[0][s] = *(const half8*)(cbase + s * 32 + q * 16 / 2);   // q*8 halves
    float c2cur = c2[half * 512 + l15];

    float m1[2][4], m2[2][4]; int i1[2][4], i2[2][4];
#pragma unroll
    for (int r = 0; r < 2; ++r)
#pragma unroll
        for (int a = 0; a < 4; ++a) {
            m1[r][a] = INFINITY; m2[r][a] = INFINITY; i1[r][a] = 0; i2[r][a] = 0;
        }

#pragma unroll 4
    for (int ch = 0; ch < 32; ++ch) {
        const int cur = ch & 1, nxt = cur ^ 1;
        float c2nxt = 0.f;
        if (ch < 31) {   // prefetch next chunk while computing this one
            const _Float16* nb = cbase + (size_t)(ch + 1) * 16 * D_DIM;
#pragma unroll
            for (int s = 0; s < 8; ++s)
                B[nxt][s] = *(const half8*)(nb + s * 32 + q * 8);
            c2nxt = c2[half * 512 + (ch + 1) * 16 + l15];
        }
        // 4 independent MFMA chains (2 row-tiles x 2 K-halves)
        floatx4 ac[2][2];
#pragma unroll
        for (int r = 0; r < 2; ++r)
#pragma unroll
            for (int h = 0; h < 2; ++h) ac[r][h] = floatx4{0.f, 0.f, 0.f, 0.f};
#pragma unroll
        for (int s = 0; s < 4; ++s) {
            ac[0][0] = __builtin_amdgcn_mfma_f32_16x16x32_f16(A[0][s],     B[cur][s],     ac[0][0], 0, 0, 0);
            ac[1][0] = __builtin_amdgcn_mfma_f32_16x16x32_f16(A[1][s],     B[cur][s],     ac[1][0], 0, 0, 0);
            ac[0][1] = __builtin_amdgcn_mfma_f32_16x16x32_f16(A[0][s + 4], B[cur][s + 4], ac[0][1], 0, 0, 0);
            ac[1][1] = __builtin_amdgcn_mfma_f32_16x16x32_f16(A[1][s + 4], B[cur][s + 4], ac[1][1], 0, 0, 0);
        }
        const int code = half * 512 + ch * 16 + l15;
#pragma unroll
        for (int r = 0; r < 2; ++r)
#pragma unroll
            for (int a = 0; a < 4; ++a) {
                float dot = ac[r][0][a] + ac[r][1][a];
                float s = fmaf(-0.001953125f, dot, c2cur);   // c2 - 2*dot (cb scaled 2^10)
                if (s < m1[r][a]) { m2[r][a] = m1[r][a]; i2[r][a] = i1[r][a]; m1[r][a] = s; i1[r][a] = code; }
                else if (s < m2[r][a]) { m2[r][a] = s; i2[r][a] = code; }
            }
        c2cur = c2nxt;
    }

    // ---- merge 32 partial top-2s per px (the only barrier in the kernel) ----
    const int part = half * 16 + l15;
#pragma unroll
    for (int r = 0; r < 2; ++r)
#pragma unroll
        for (int a = 0; a < 4; ++a) {
            int px = pxg * 32 + r * 16 + q * 4 + a;
            int o = part * 65 + px;
            scr[0][o] = m1[r][a];
            scr[1][o] = __int_as_float(i1[r][a]);
            scr[2][o] = m2[r][a];
            scr[3][o] = __int_as_float(i2[r][a]);
        }
    __syncthreads();
    if (t < 64) {
        float S[4] = {INFINITY, INFINITY, INFINITY, INFINITY};
        int   I[4] = {0x7fffffff, 0x7fffffff, 0x7fffffff, 0x7fffffff};
        for (int p = 0; p < 32; ++p) {   // reads: stride 65 -> 2-way, conflict-free
            int o = p * 65 + t;
            ins4v(scr[0][o], __float_as_int(scr[1][o]), S, I);
            ins4v(scr[2][o], __float_as_int(scr[3][o]), S, I);
        }
        int P = px0 + t;
        idxbuf[P] = I[0];
        out_idx[P] = (float)I[0];
        if (S[1] - S[0] <= MARGIN) {     // near-tie: queue for exact reference emulation
            int pos = atomicAdd(cnt, 1);
            if (pos < FLAG_CAP) {
                flagPx[pos] = P;
                flagTop[2 * pos]     = floatx4{S[0], (float)I[0], S[1], (float)I[1]};
                flagTop[2 * pos + 1] = floatx4{S[2], (float)I[2], S[3], (float)I[3]};
            }
        }
    }
}

// ---------------- kernel 2: wave-per-flagged-pixel reference-fp32 emulation --------
// ref (numpy fp32): d2_k = fl(fl(x2 - fl(2*mm_k)) + c2_k); argmin, first-index ties.
__global__ __launch_bounds__(256) void rescore_wave(
        const float* __restrict__ x, const float* __restrict__ cb,
        const float* __restrict__ c2, const int* __restrict__ cnt,
        const int* __restrict__ flagPx, const floatx4* __restrict__ flagTop,
        float* __restrict__ out_idx, int* __restrict__ idxbuf) {
    const int wglobal = blockIdx.x * 4 + (threadIdx.x >> 6);
    const int l = threadIdx.x & 63;
    int n = *cnt; if (n > FLAG_CAP) n = FLAG_CAP;
    for (int i = wglobal; i < n; i += 1024) {
        int P = flagPx[i];
        floatx4 ta = flagTop[2 * i], tb = flagTop[2 * i + 1];
        float s1 = ta[0];
        float cs[4] = {ta[0], ta[2], tb[0], tb[2]};
        int   ck[4] = {(int)ta[1], (int)ta[3], (int)tb[1], (int)tb[3]};
        int nc = 1;
        while (nc < 4 && cs[nc] - s1 <= MARGIN) ++nc;

        const float* xcol = x + (size_t)(P >> 10) * D_DIM * HW + (P & 1023);

        // x2 with numpy's exact pairwise order: lanes 0..15 run the 8-acc chains
        float rj = 0.f;
        if (l < 16) {
            int h = l >> 3, j = l & 7;
            const float* p = xcol + (size_t)(h * 128) * HW;
            float v0 = p[(size_t)j * HW];
            rj = __fmul_rn(v0, v0);
            for (int ii = 1; ii < 16; ++ii) {
                float v = p[(size_t)(ii * 8 + j) * HW];
                rj = __fadd_rn(rj, __fmul_rn(v, v));
            }
        }
        float r0 = __shfl(rj, 0), r1 = __shfl(rj, 1), r2 = __shfl(rj, 2), r3 = __shfl(rj, 3);
        float r4 = __shfl(rj, 4), r5 = __shfl(rj, 5), r6 = __shfl(rj, 6), r7 = __shfl(rj, 7);
        float h0 = __fadd_rn(__fadd_rn(__fadd_rn(r0, r1), __fadd_rn(r2, r3)),
                             __fadd_rn(__fadd_rn(r4, r5), __fadd_rn(r6, r7)));
        r0 = __shfl(rj, 8); r1 = __shfl(rj, 9); r2 = __shfl(rj, 10); r3 = __shfl(rj, 11);
        r4 = __shfl(rj, 12); r5 = __shfl(rj, 13); r6 = __shfl(rj, 14); r7 = __shfl(rj, 15);
        float h1 = __fadd_rn(__fadd_rn(__fadd_rn(r0, r1), __fadd_rn(r2, r3)),
                             __fadd_rn(__fadd_rn(r4, r5), __fadd_rn(r6, r7)));
        float x2 = __fadd_rn(h0, h1);

        // f64 dots (stand-in for faithful sgemm): lane covers d = l, l+64, l+128, l+192
        float xv[4];
#pragma unroll
        for (int u = 0; u < 4; ++u) xv[u] = xcol[(size_t)(l + u * 64) * HW];
        double accd[4] = {0.0, 0.0, 0.0, 0.0};
        for (int jc = 0; jc < nc; ++jc) {
            const float* cr = cb + (size_t)ck[jc] * D_DIM;
            double a = 0.0;
#pragma unroll
            for (int u = 0; u < 4; ++u) a += (double)xv[u] * (double)cr[l + u * 64];
#pragma unroll
            for (int off = 32; off > 0; off >>= 1) a += __shfl_down(a, off);
            accd[jc] = a;
        }
        if (l == 0) {
            float bd = INFINITY; int bi = 0x7fffffff;
            for (int jc = 0; jc < nc; ++jc) {
                float mm = (float)accd[jc];
                float t1 = __fsub_rn(x2, __fmul_rn(2.0f, mm));
                float Dq = __fadd_rn(t1, c2[ck[jc]]);
                if (Dq < bd || (Dq == bd && ck[jc] < bi)) { bd = Dq; bi = ck[jc]; }
            }
            idxbuf[P] = bi;
            out_idx[P] = (float)bi;
        }
    }
}

// ---------------- kernel 3: quantized write + per-block loss partials ----------------
__global__ __launch_bounds__(128) void quantize_loss_kernel(
        const float* __restrict__ x, const float* __restrict__ cb,
        const int* __restrict__ idxbuf, float* __restrict__ out_q,
        double* __restrict__ partials) {
    int P = blockIdx.x * 128 + threadIdx.x;
    int bimg = P >> 10, hw = P & 1023;
    const float* xb = x + (size_t)bimg * D_DIM * HW + hw;
    float* qb = out_q + (size_t)bimg * D_DIM * HW + hw;
    const floatx4* crow = (const floatx4*)(cb + (size_t)idxbuf[P] * D_DIM);
    float lsum = 0.f;
#pragma unroll 4
    for (int d4 = 0; d4 < D_DIM / 4; ++d4) {
        floatx4 qv = crow[d4];
#pragma unroll
        for (int j = 0; j < 4; ++j) {
            size_t off = (size_t)(d4 * 4 + j) * HW;
            float xv = xb[off];
            qb[off] = qv[j];
            float df = qv[j] - xv;
            lsum = fmaf(df, df, lsum);
        }
    }
    double ds = (double)lsum;
#pragma unroll
    for (int off = 32; off > 0; off >>= 1) ds += __shfl_down(ds, off);
    __shared__ double sred[2];
    if ((threadIdx.x & 63) == 0) sred[threadIdx.x >> 6] = ds;
    __syncthreads();
    if (threadIdx.x == 0) partials[blockIdx.x] = sred[0] + sred[1];
}

// ---------------- kernel 4: loss scalars ----------------
__global__ __launch_bounds__(64) void finalize_loss(const double* __restrict__ partials,
                                                    float* __restrict__ out) {
    double s = 0.0;
    for (int i = threadIdx.x; i < 256; i += 64) s += partials[i];
#pragma unroll
    for (int off = 32; off > 0; off >>= 1) s += __shfl_down(s, off);
    if (threadIdx.x == 0) {
        double m = s / (double)NELEM;
        out[OFF_QLOSS] = (float)m;
        out[OFF_ELOSS] = (float)m;            // numerically identical to q_loss
        out[OFF_VQ]    = (float)(1.25 * m);   // q + 0.25*e
    }
}

extern "C" void kernel_launch(void* const* d_in, const int* in_sizes, int n_in,
                              void* d_out, int out_size, void* d_ws, size_t ws_size,
                              hipStream_t stream) {
    const float* x  = (const float*)d_in[0];   // (32,256,32,32)
    const float* cb = (const float*)d_in[1];   // (1024,256)
    float* out = (float*)d_out;
    char* ws = (char*)d_ws;

    int*     idxbuf  = (int*)(ws + WS_IDX);
    float*   c2      = (float*)(ws + WS_C2);
    int*     cnt     = (int*)(ws + WS_CNT);
    double*  partials= (double*)(ws + WS_PART);
    int*     flagPx  = (int*)(ws + WS_FLAGPX);
    floatx4* flagTop = (floatx4*)(ws + WS_FLAGTOP);

    // fp16 codebook in the quantized-output region (fully overwritten by kernel 3)
    _Float16* cb16 = (_Float16*)out;

    prep_kernel<<<260, 256, 0, stream>>>(cb, cb16, c2, cnt);
    gemm_stream<<<512, 256, 0, stream>>>(x, cb16, c2, out + OFF_IDX, idxbuf,
                                         cnt, flagPx, flagTop);
    rescore_wave<<<256, 256, 0, stream>>>(x, cb, c2, cnt, flagPx, flagTop,
                                          out + OFF_IDX, idxbuf);
    quantize_loss_kernel<<<NPIX / 128, 128, 0, stream>>>(x, cb, idxbuf, out, partials);
    finalize_loss<<<1, 64, 0, stream>>>(partials, out);
}